// Round 1
// baseline (33.243 us; speedup 1.0000x reference)
//
#include <hip/hip_runtime.h>
#include <hip/hip_bf16.h>

#define BATCH 4096
#define FEAT  64
#define LW    64
#define KH    5
#define KW    9
#define RH    5
#define PADL  4
#define CUT   5   // mask: h==KH-1 && ww>=CUT -> zeroed weight

typedef __attribute__((ext_vector_type(8))) short bf16x8;
typedef __attribute__((ext_vector_type(4))) float f32x4;

__device__ __forceinline__ short f2bf(float x) {
    union { float f; unsigned u; } v; v.f = x;
    unsigned r = v.u + 0x7FFFu + ((v.u >> 16) & 1u);  // round-to-nearest-even
    return (short)(r >> 16);
}

// Transpose + mask + convert weights: W[h][ww][c][f] f32 -> Wt[p][f][c] bf16
__global__ __launch_bounds__(256) void wprep_kernel(const float* __restrict__ W,
                                                    short* __restrict__ Wt) {
    __shared__ short T[64][72];   // [f][c], padded stride
    int p = blockIdx.x;           // 0..44
    int h = p / KW, ww = p % KW;
    bool masked = (h == KH - 1) && (ww >= CUT);
    int t = threadIdx.x;
    const float* src = W + p * 4096;
    for (int i = 0; i < 16; ++i) {
        int e = i * 256 + t;      // enumerates (c,f), f fastest -> coalesced read
        int c = e >> 6, f = e & 63;
        float val = masked ? 0.f : src[e];
        T[f][c] = f2bf(val);
    }
    __syncthreads();
    short* dst = Wt + p * 4096;
    for (int i = 0; i < 16; ++i) {
        int e = i * 256 + t;      // enumerates (f,c), c fastest -> coalesced write
        int f = e >> 6, c = e & 63;
        dst[e] = T[f][c];
    }
}

template<bool USE_WS>
__global__ __launch_bounds__(256) void conv_kernel(
    const float* __restrict__ inputs, const float* __restrict__ cache,
    const float* __restrict__ Wf32, const short* __restrict__ Wt,
    const float* __restrict__ bias, const int* __restrict__ idxp,
    float* __restrict__ out)
{
    const int lane = threadIdx.x & 63;
    const int wave = threadIdx.x >> 6;
    const int n    = lane & 15;     // B col offset (f) and A row offset (m)
    const int g    = lane >> 4;     // k-group 0..3
    const int r0   = blockIdx.x * 16;
    const int fbase = wave * 16;

    const int index   = idxp[0];
    int index_w = index % LW; if (index_w < 0) index_w += LW;
    const bool upd   = (index >= 0);
    const bool shift = upd && (index_w == 0);

    f32x4 acc0 = {0.f, 0.f, 0.f, 0.f};
    f32x4 acc1 = {0.f, 0.f, 0.f, 0.f};

    const int b = r0 + n;                       // this lane's A (batch) row
    const float* inrow = inputs + (long)b * FEAT;
    const int k0 = g * 8;

    int pcnt = 0;
    for (int h = 0; h < KH; ++h) {
        for (int ww = 0; ww < KW; ++ww) {
            if (h == KH - 1 && ww >= CUT) continue;           // weight mask
            const int col = index_w - PADL + ww;
            const bool is_input = upd && (h == KH - 1) && (ww == PADL);
            if (!is_input) {
                if (col < 0 || col >= LW) continue;           // zero padding
                if (shift && h == KH - 1) continue;           // shifted-in zero row
            }
            const int hh = shift ? h + 1 : h;

            const float* asrc = is_input
                ? inrow
                : cache + (((long)b * RH + hh) * LW + col) * FEAT;

            // A fragments: c = s*32 + g*8 + j
            f32x4 x0 = *(const f32x4*)(asrc + k0);
            f32x4 x1 = *(const f32x4*)(asrc + k0 + 4);
            f32x4 x2 = *(const f32x4*)(asrc + 32 + k0);
            f32x4 x3 = *(const f32x4*)(asrc + 32 + k0 + 4);
            bf16x8 a0, a1;
            a0[0]=f2bf(x0[0]); a0[1]=f2bf(x0[1]); a0[2]=f2bf(x0[2]); a0[3]=f2bf(x0[3]);
            a0[4]=f2bf(x1[0]); a0[5]=f2bf(x1[1]); a0[6]=f2bf(x1[2]); a0[7]=f2bf(x1[3]);
            a1[0]=f2bf(x2[0]); a1[1]=f2bf(x2[1]); a1[2]=f2bf(x2[2]); a1[3]=f2bf(x2[3]);
            a1[4]=f2bf(x3[0]); a1[5]=f2bf(x3[1]); a1[6]=f2bf(x3[2]); a1[7]=f2bf(x3[3]);

            // B fragments
            const int p = h * KW + ww;
            bf16x8 b0, b1;
            if (USE_WS) {
                const short* wsrc = Wt + ((long)(p * FEAT) + (fbase + n)) * FEAT;
                b0 = *(const bf16x8*)(wsrc + k0);
                b1 = *(const bf16x8*)(wsrc + 32 + k0);
            } else {
                const float* wsrc = Wf32 + (long)p * FEAT * FEAT + (fbase + n);
                #pragma unroll
                for (int j = 0; j < 8; ++j) {
                    b0[j] = f2bf(wsrc[(k0 + j) * FEAT]);
                    b1[j] = f2bf(wsrc[(32 + k0 + j) * FEAT]);
                }
            }

            if (pcnt & 1) {
                acc1 = __builtin_amdgcn_mfma_f32_16x16x32_bf16(a0, b0, acc1, 0, 0, 0);
                acc1 = __builtin_amdgcn_mfma_f32_16x16x32_bf16(a1, b1, acc1, 0, 0, 0);
            } else {
                acc0 = __builtin_amdgcn_mfma_f32_16x16x32_bf16(a0, b0, acc0, 0, 0, 0);
                acc0 = __builtin_amdgcn_mfma_f32_16x16x32_bf16(a1, b1, acc0, 0, 0, 0);
            }
            ++pcnt;
        }
    }

    const float bv = bias[fbase + n];
    // D layout: col = lane&15 -> f, row = (lane>>4)*4 + i -> b
    #pragma unroll
    for (int i = 0; i < 4; ++i) {
        const int ob = r0 + g * 4 + i;
        out[(long)ob * FEAT + fbase + n] = acc0[i] + acc1[i] + bv;
    }
}

extern "C" void kernel_launch(void* const* d_in, const int* in_sizes, int n_in,
                              void* d_out, int out_size, void* d_ws, size_t ws_size,
                              hipStream_t stream) {
    const float* inputs = (const float*)d_in[0];
    const float* cache  = (const float*)d_in[1];
    const float* kern   = (const float*)d_in[2];
    const float* bias   = (const float*)d_in[3];
    const int*   idx    = (const int*)d_in[4];
    float* out = (float*)d_out;

    const size_t ws_needed = (size_t)KH * KW * FEAT * FEAT * sizeof(short);
    if (ws_size >= ws_needed) {
        short* Wt = (short*)d_ws;
        wprep_kernel<<<KH * KW, 256, 0, stream>>>(kern, Wt);
        conv_kernel<true><<<BATCH / 16, 256, 0, stream>>>(
            inputs, cache, kern, Wt, bias, idx, out);
    } else {
        conv_kernel<false><<<BATCH / 16, 256, 0, stream>>>(
            inputs, cache, kern, nullptr, bias, idx, out);
    }
}

// Round 2
// 27.030 us; speedup vs baseline: 1.2299x; 1.2299x over previous
//
#include <hip/hip_runtime.h>
#include <hip/hip_bf16.h>

#define BATCH 4096
#define FEAT  64
#define LW    64
#define KH    5
#define KW    9
#define RH    5
#define PADL  4
#define CUT   5    // mask: h==KH-1 && ww>=CUT -> zero weight (compile-time)
#define NPOS  41   // active positions p = h*KW+ww = 0..40 (41..44 are compile-masked)
#define NKQ   16   // K-split: waves per block

typedef __attribute__((ext_vector_type(8))) short bf16x8;
typedef __attribute__((ext_vector_type(4))) float f32x4;

__device__ __forceinline__ short f2bf(float x) {
    union { float f; unsigned u; } v; v.f = x;
    unsigned r = v.u + 0x7FFFu + ((v.u >> 16) & 1u);  // RNE
    return (short)(r >> 16);
}

__device__ __forceinline__ bf16x8 cvt8(f32x4 x0, f32x4 x1) {
    bf16x8 a;
    a[0]=f2bf(x0[0]); a[1]=f2bf(x0[1]); a[2]=f2bf(x0[2]); a[3]=f2bf(x0[3]);
    a[4]=f2bf(x1[0]); a[5]=f2bf(x1[1]); a[6]=f2bf(x1[2]); a[7]=f2bf(x1[3]);
    return a;
}

// Weights: mask + runtime zeroing (pad cols / shift row) + transpose + bf16.
// W[h][ww][c][f] f32  ->  Wt[p][f][c] bf16, with W'=0 wherever the conv's
// clamped A-read must not contribute.
__global__ __launch_bounds__(256) void wprep_kernel(
    const float* __restrict__ W, const int* __restrict__ idxp,
    short* __restrict__ Wt)
{
    __shared__ short T[64][72];
    const int p = blockIdx.x;            // 0..44
    const int h = p / KW, ww = p % KW;
    const int index = idxp[0];
    int index_w = ((index % LW) + LW) % LW;
    const bool upd   = index >= 0;
    const bool shift = upd && (index_w == 0);
    const bool is_input = upd && (h == KH - 1) && (ww == PADL);
    const int col = index_w - PADL + ww;
    const bool zero = (h == KH - 1 && ww >= CUT)
                   || (!is_input && (col < 0 || col >= LW))
                   || (!is_input && shift && h == KH - 1);
    const int t = threadIdx.x;
    const float* src = W + p * 4096;
    for (int i = 0; i < 16; ++i) {
        int e = i * 256 + t;             // (c,f), f fastest -> coalesced read
        int c = e >> 6, f = e & 63;
        T[f][c] = zero ? (short)0 : f2bf(src[e]);
    }
    __syncthreads();
    short* dst = Wt + p * 4096;
    for (int i = 0; i < 16; ++i) {
        int e = i * 256 + t;             // (f,c), c fastest -> coalesced write
        dst[e] = T[e >> 6][e & 63];
    }
}

// One K-chunk of positions, fully unrolled (compile-time h,ww), branch-free.
template<int KQ>
__device__ __forceinline__ void chunk(
    const float* __restrict__ crow, const float* __restrict__ inrow,
    int index_w, bool upd, bool shift, const short* __restrict__ Wt,
    int n, int k0, f32x4 acc[4])
{
    constexpr int P0 = (NPOS * KQ) / NKQ;
    constexpr int P1 = (NPOS * (KQ + 1)) / NKQ;
    #pragma unroll
    for (int p = P0; p < P1; ++p) {
        constexpr int dummy = 0; (void)dummy;
        const int h = p / KW, ww = p % KW;          // compile-time
        int col  = index_w - PADL + ww;
        int colc = min(max(col, 0), LW - 1);        // clamp (zero-weighted if OOB)
        int hh   = shift ? min(h + 1, RH - 1) : h;  // clamped (zero-weighted row)
        const float* aptr = crow + (hh * LW + colc) * FEAT;
        if (h == KH - 1 && ww == PADL) {            // compile-time position check
            if (upd) aptr = inrow;                  // uniform runtime select
        }
        f32x4 x0 = *(const f32x4*)(aptr + k0);
        f32x4 x1 = *(const f32x4*)(aptr + k0 + 4);
        f32x4 x2 = *(const f32x4*)(aptr + 32 + k0);
        f32x4 x3 = *(const f32x4*)(aptr + 32 + k0 + 4);
        bf16x8 a0 = cvt8(x0, x1);
        bf16x8 a1 = cvt8(x2, x3);
        const short* wbase = Wt + p * 4096 + n * 64;
        #pragma unroll
        for (int ft = 0; ft < 4; ++ft) {
            bf16x8 b0 = *(const bf16x8*)(wbase + ft * 1024 + k0);
            bf16x8 b1 = *(const bf16x8*)(wbase + ft * 1024 + 32 + k0);
            acc[ft] = __builtin_amdgcn_mfma_f32_16x16x32_bf16(a0, b0, acc[ft], 0, 0, 0);
            acc[ft] = __builtin_amdgcn_mfma_f32_16x16x32_bf16(a1, b1, acc[ft], 0, 0, 0);
        }
    }
}

__global__ __launch_bounds__(1024) void conv_kernel(
    const float* __restrict__ inputs, const float* __restrict__ cache,
    const short* __restrict__ Wt, const float* __restrict__ bias,
    const int* __restrict__ idxp, float* __restrict__ out)
{
    __shared__ float Lacc[NKQ][16][65];   // [wave][m][f], padded stride

    const int t    = threadIdx.x;
    const int lane = t & 63;
    const int wv   = t >> 6;              // 0..15 = K-chunk id
    const int n    = lane & 15;           // A row offset (m) and B col offset (f)
    const int g    = lane >> 4;           // k-group
    const int r0   = blockIdx.x * 16;

    const int index = idxp[0];
    int index_w = ((index % LW) + LW) % LW;
    const bool upd   = index >= 0;
    const bool shift = upd && (index_w == 0);

    const long b = r0 + n;
    const float* crow  = cache  + b * (RH * LW * FEAT);
    const float* inrow = inputs + b * FEAT;
    const int k0 = g * 8;

    f32x4 acc[4] = {{0,0,0,0},{0,0,0,0},{0,0,0,0},{0,0,0,0}};

    switch (wv) {
        case 0:  chunk<0 >(crow, inrow, index_w, upd, shift, Wt, n, k0, acc); break;
        case 1:  chunk<1 >(crow, inrow, index_w, upd, shift, Wt, n, k0, acc); break;
        case 2:  chunk<2 >(crow, inrow, index_w, upd, shift, Wt, n, k0, acc); break;
        case 3:  chunk<3 >(crow, inrow, index_w, upd, shift, Wt, n, k0, acc); break;
        case 4:  chunk<4 >(crow, inrow, index_w, upd, shift, Wt, n, k0, acc); break;
        case 5:  chunk<5 >(crow, inrow, index_w, upd, shift, Wt, n, k0, acc); break;
        case 6:  chunk<6 >(crow, inrow, index_w, upd, shift, Wt, n, k0, acc); break;
        case 7:  chunk<7 >(crow, inrow, index_w, upd, shift, Wt, n, k0, acc); break;
        case 8:  chunk<8 >(crow, inrow, index_w, upd, shift, Wt, n, k0, acc); break;
        case 9:  chunk<9 >(crow, inrow, index_w, upd, shift, Wt, n, k0, acc); break;
        case 10: chunk<10>(crow, inrow, index_w, upd, shift, Wt, n, k0, acc); break;
        case 11: chunk<11>(crow, inrow, index_w, upd, shift, Wt, n, k0, acc); break;
        case 12: chunk<12>(crow, inrow, index_w, upd, shift, Wt, n, k0, acc); break;
        case 13: chunk<13>(crow, inrow, index_w, upd, shift, Wt, n, k0, acc); break;
        case 14: chunk<14>(crow, inrow, index_w, upd, shift, Wt, n, k0, acc); break;
        default: chunk<15>(crow, inrow, index_w, upd, shift, Wt, n, k0, acc); break;
    }

    // D layout: col f = ft*16+n, row m = g*4+i
    #pragma unroll
    for (int ft = 0; ft < 4; ++ft)
        #pragma unroll
        for (int i = 0; i < 4; ++i)
            Lacc[wv][g * 4 + i][ft * 16 + n] = acc[ft][i];

    __syncthreads();

    // Reduce over the 16 K-chunks: thread t -> (m = t>>6 = wave, f = lane)
    const int m = wv;
    const int f = lane;
    float s = bias[f];
    #pragma unroll
    for (int w = 0; w < NKQ; ++w) s += Lacc[w][m][f];
    out[(long)(r0 + m) * FEAT + f] = s;
}

extern "C" void kernel_launch(void* const* d_in, const int* in_sizes, int n_in,
                              void* d_out, int out_size, void* d_ws, size_t ws_size,
                              hipStream_t stream) {
    const float* inputs = (const float*)d_in[0];
    const float* cache  = (const float*)d_in[1];
    const float* kern   = (const float*)d_in[2];
    const float* bias   = (const float*)d_in[3];
    const int*   idx    = (const int*)d_in[4];
    float* out = (float*)d_out;

    short* Wt = (short*)d_ws;   // needs 45*4096*2 = 368,640 B (verified fits in R1)
    wprep_kernel<<<KH * KW, 256, 0, stream>>>(kern, idx, Wt);
    conv_kernel<<<BATCH / 16, 1024, 0, stream>>>(inputs, cache, Wt, bias, idx, out);
}